// Round 8
// baseline (1619.086 us; speedup 1.0000x reference)
//
#include <hip/hip_runtime.h>
#include <math.h>

#define NLEN   32768
#define NATOMS 256
#define ATOM_S 512
#define NSTEPS 16
#define NCHAN  8   // 2 signals x 4 batches
#define NSEL   (NCHAN * NSTEPS)   // 128

// ---------- packed ordered key helpers ----------
__device__ __forceinline__ unsigned int ord32(float x) {
    unsigned int u = __float_as_uint(x);
    return (u & 0x80000000u) ? ~u : (u | 0x80000000u);
}
__device__ __forceinline__ float unord32(unsigned int o) {
    unsigned int u = (o & 0x80000000u) ? (o & 0x7FFFFFFFu) : ~o;
    return __uint_as_float(u);
}
// bigger key = bigger v, then smaller atom, then smaller position
__device__ __forceinline__ unsigned long long packkey(float v, int a, int q) {
    return ((unsigned long long)ord32(v) << 23)
         | ((unsigned long long)((255 - a) & 255) << 15)
         | (unsigned long long)((NLEN - 1 - q) & 32767);
}

// ---------- prep: normalize dict (transposed), init BOTH residual buffers ----------
__global__ void prep_kernel(const float* __restrict__ recon,
                            const float* __restrict__ target,
                            const float* __restrict__ d,
                            float* __restrict__ d_t,
                            float* __restrict__ res0,
                            float* __restrict__ res1,
                            unsigned long long* __restrict__ mkey,
                            unsigned long long* __restrict__ stepkey) {
    int b = blockIdx.x, t = threadIdx.x;
    if (b < NATOMS) {
        __shared__ float red[256];
        float x0 = d[b * ATOM_S + t];
        float x1 = d[b * ATOM_S + 256 + t];
        red[t] = x0 * x0 + x1 * x1;
        __syncthreads();
        for (int off = 128; off; off >>= 1) {
            if (t < off) red[t] += red[t + off];
            __syncthreads();
        }
        float denom = sqrtf(red[0]) + 1e-8f;
        int s0 = t, s1 = t + 256;
        d_t[((s0 >> 2) * NATOMS + b) * 4 + (s0 & 3)] = x0 / denom;
        d_t[((s1 >> 2) * NATOMS + b) * 4 + (s1 & 3)] = x1 / denom;
    } else if (b < NATOMS + 32) {
        int blk = b - NATOMS;
        for (int i = 0; i < 32; ++i) {
            int idx = blk * 8192 + i * 256 + t;     // 0 .. 262143
            int c = idx >> 15, q = idx & (NLEN - 1);
            float x = (c < 4) ? recon[c * NLEN + q] : target[(c - 4) * NLEN + q];
            res0[idx] = x;
            res1[idx] = x;
            mkey[idx] = 0ull;
        }
    } else {
        if (t < NSEL) stepkey[t] = 0ull;
    }
}

// ---------- 16 FMAs for one atom x 4 sliding positions (fixed order) ----------
__device__ __forceinline__ void fma16(float acc[4], float4 dv,
                                      const float4& rc, const float4& rn) {
    acc[0] = fmaf(rc.x, dv.x, acc[0]); acc[0] = fmaf(rc.y, dv.y, acc[0]);
    acc[0] = fmaf(rc.z, dv.z, acc[0]); acc[0] = fmaf(rc.w, dv.w, acc[0]);
    acc[1] = fmaf(rc.y, dv.x, acc[1]); acc[1] = fmaf(rc.z, dv.y, acc[1]);
    acc[1] = fmaf(rc.w, dv.z, acc[1]); acc[1] = fmaf(rn.x, dv.w, acc[1]);
    acc[2] = fmaf(rc.z, dv.x, acc[2]); acc[2] = fmaf(rc.w, dv.y, acc[2]);
    acc[2] = fmaf(rn.x, dv.z, acc[2]); acc[2] = fmaf(rn.y, dv.w, acc[2]);
    acc[3] = fmaf(rc.w, dv.x, acc[3]); acc[3] = fmaf(rn.x, dv.y, acc[3]);
    acc[3] = fmaf(rn.y, dv.z, acc[3]); acc[3] = fmaf(rn.z, dv.w, acc[3]);
}

// ---------- 8 FMAs for one atom x 2 sliding positions (same per-pos tap order) ----------
__device__ __forceinline__ void fma8(float acc[2], float4 dv,
                                     const float4& rc, float rn0) {
    acc[0] = fmaf(rc.x, dv.x, acc[0]); acc[0] = fmaf(rc.y, dv.y, acc[0]);
    acc[0] = fmaf(rc.z, dv.z, acc[0]); acc[0] = fmaf(rc.w, dv.w, acc[0]);
    acc[1] = fmaf(rc.y, dv.x, acc[1]); acc[1] = fmaf(rc.z, dv.y, acc[1]);
    acc[1] = fmaf(rc.w, dv.z, acc[1]); acc[1] = fmaf(rn0,  dv.w, acc[1]);
}

// ---------- 8-atom x 4-pos dot with 2-deep d_t register prefetch ----------
// Same FMA order per (atom, position) as the original dot8 -> bit-identical.
// NOTE: prefetches up to 255 float4 past d_t's end (lands in res0, unused).
__device__ __forceinline__ void dot8p(const float* __restrict__ lres, int base,
                                      const float4* __restrict__ dt0,
                                      float acc[8][4]) {
#pragma unroll
    for (int aa = 0; aa < 8; ++aa)
#pragma unroll
        for (int j = 0; j < 4; ++j) acc[aa][j] = 0.0f;
    float4 dva[8], dvb[8];
#pragma unroll
    for (int aa = 0; aa < 8; ++aa) dva[aa] = dt0[aa];
    float4 rc = *(const float4*)&lres[base];
    const float4* dtp = dt0;
#pragma unroll 1
    for (int s4 = 0; s4 < ATOM_S / 4; s4 += 2) {
        float4 rn = *(const float4*)&lres[base + s4 * 4 + 4];
#pragma unroll
        for (int aa = 0; aa < 8; ++aa) dvb[aa] = dtp[NATOMS + aa];
#pragma unroll
        for (int aa = 0; aa < 8; ++aa) fma16(acc[aa], dva[aa], rc, rn);
        float4 rn2 = *(const float4*)&lres[base + s4 * 4 + 8];
#pragma unroll
        for (int aa = 0; aa < 8; ++aa) dva[aa] = dtp[2 * NATOMS + aa];
#pragma unroll
        for (int aa = 0; aa < 8; ++aa) fma16(acc[aa], dvb[aa], rn, rn2);
        dtp += 2 * NATOMS;
        rc = rn2;
    }
}

// ---------- 8-atom x 2-pos dot with 2-deep d_t register prefetch ----------
// Per-(atom,pos) tap order s=0..511 sequential -> bit-identical values.
__device__ __forceinline__ void dot8p2(const float* __restrict__ lres, int base,
                                       const float4* __restrict__ dt0,
                                       float acc[8][2]) {
#pragma unroll
    for (int aa = 0; aa < 8; ++aa) { acc[aa][0] = 0.0f; acc[aa][1] = 0.0f; }
    float4 dva[8], dvb[8];
#pragma unroll
    for (int aa = 0; aa < 8; ++aa) dva[aa] = dt0[aa];
    const float4* dtp = dt0;
#pragma unroll 1
    for (int s4 = 0; s4 < ATOM_S / 4; s4 += 2) {
        float4 rcA = *(const float4*)&lres[base + s4 * 4];
        float  rnA = lres[base + s4 * 4 + 4];
#pragma unroll
        for (int aa = 0; aa < 8; ++aa) dvb[aa] = dtp[NATOMS + aa];
#pragma unroll
        for (int aa = 0; aa < 8; ++aa) fma8(acc[aa], dva[aa], rcA, rnA);
        float4 rcB = *(const float4*)&lres[base + s4 * 4 + 4];
        float  rnB = lres[base + s4 * 4 + 8];
#pragma unroll
        for (int aa = 0; aa < 8; ++aa) dva[aa] = dtp[2 * NATOMS + aa];
#pragma unroll
        for (int aa = 0; aa < 8; ++aa) fma8(acc[aa], dvb[aa], rcB, rnB);
        dtp += 2 * NATOMS;
    }
}

// ---------- initial full correlation; per-position max + step-0 argmax ----------
// grid (32 tiles of 1024 pos, 8 channels, 8 atom-groups of 32), 256 threads
__global__ __launch_bounds__(256) void init_conv(const float* __restrict__ residual,
                                                 const float* __restrict__ d_t,
                                                 unsigned long long* __restrict__ mkey,
                                                 unsigned long long* __restrict__ stepkey) {
    __shared__ __align__(16) float lres[1536 + 16];
    __shared__ unsigned long long kred[256];
    int q0 = blockIdx.x * 1024;
    int c  = blockIdx.y;
    int ag = blockIdx.z;
    int t  = threadIdx.x;
    const float* res = residual + c * NLEN;
    for (int i = t; i < 1536; i += 256) {
        int g = q0 + i;
        lres[i] = (g < NLEN) ? res[g] : 0.0f;
    }
    __syncthreads();

    int base = t * 4;
    float bestv[4] = {-INFINITY, -INFINITY, -INFINITY, -INFINITY};
    int   besta[4] = {0, 0, 0, 0};
#pragma unroll 1
    for (int g8 = 0; g8 < 4; ++g8) {
        int a0 = ag * 32 + g8 * 8;
        float acc[8][4];
        dot8p(lres, base, (const float4*)d_t + a0, acc);
#pragma unroll
        for (int aa = 0; aa < 8; ++aa)
#pragma unroll
            for (int j = 0; j < 4; ++j)
                if (acc[aa][j] > bestv[j]) { bestv[j] = acc[aa][j]; besta[j] = a0 + aa; }
    }
    unsigned long long* mk = mkey + c * NLEN;
    unsigned long long myk = 0ull;
#pragma unroll
    for (int j = 0; j < 4; ++j) {
        int q = q0 + base + j;
        unsigned long long k = packkey(bestv[j], besta[j], q);
        atomicMax(&mk[q], k);
        if (k > myk) myk = k;
    }
    kred[t] = myk;
    __syncthreads();
    for (int off = 128; off; off >>= 1) {
        if (t < off) { if (kred[t + off] > kred[t]) kred[t] = kred[t + off]; }
        __syncthreads();
    }
    if (t == 0) atomicMax(&stepkey[c], kred[0]);
}

// ---------- per-step kernel: 512 blocks x 256 threads (2 blocks/CU) ----------
// block b: c = b>>6, r = b&63.
//   window duty : own 16 positions [w0+16r, w0+16r+16) x ALL 256 atoms
//                 (thread: 8 atoms x 2 positions, dot8p2); exclusive mkey store.
//   scan duty   : 512-position slice r of mkey outside [w0,w1).
//   writer duty : r==0 blocks advance buf_next from R_{k-1} to R_{k+1}.
__global__ __launch_bounds__(256) void step_kernel(const float* __restrict__ buf_cur,
                                                   float* __restrict__ buf_next,
                                                   const float* __restrict__ d_t,
                                                   unsigned long long* __restrict__ mkey,
                                                   unsigned long long* __restrict__ stepkey,
                                                   int k) {
    int b = blockIdx.x, t = threadIdx.x;
    int c = b >> 6, r = b & 63;
    __shared__ __align__(16) float lres[528 + 16];
    __shared__ unsigned long long kk[32 * 17];
    __shared__ unsigned long long kred[256];

    unsigned long long key = stepkey[k * NCHAN + c];
    int a = 255 - (int)((key >> 15) & 255);
    int p = (NLEN - 1) - (int)(key & 32767);
    float v = unord32((unsigned int)(key >> 23));
    int w0 = max(0, p - (ATOM_S - 1));
    int w1 = min(NLEN, p + ATOM_S);
    int qstart = w0 + r * 16;

    // ---- writer duty (r==0): sequential deltas, bitwise = reference order ----
    if (r == 0) {
        float* bn = buf_next + c * NLEN;
        int s0 = (k > 0) ? (k - 1) : 0;
        for (int s = s0; s <= k; ++s) {
            unsigned long long ks = stepkey[s * NCHAN + c];
            int as = 255 - (int)((ks >> 15) & 255);
            int ps = (NLEN - 1) - (int)(ks & 32767);
            float vs = unord32((unsigned int)(ks >> 23));
            for (int i = t; i < ATOM_S; i += 256) {
                int q = ps + i;
                if (q < NLEN) {
                    float dval = d_t[((i >> 2) * NATOMS + as) * 4 + (i & 3)];
                    bn[q] = __fsub_rn(bn[q], __fmul_rn(vs, dval));
                }
            }
            __syncthreads();   // order delta_{k-1} before delta_k (ranges may overlap)
        }
    }

    // ---- stage lres (apply delta_k on the fly; same rounding as writer) ----
    const float* rcur = buf_cur + c * NLEN;
    for (int i = t; i < 528; i += 256) {
        int g = qstart + i;
        float x = (g < NLEN) ? rcur[g] : 0.0f;
        int s = g - p;
        if (s >= 0 && s < ATOM_S && g < NLEN) {
            float dval = d_t[((s >> 2) * NATOMS + a) * 4 + (s & 3)];
            x = __fsub_rn(x, __fmul_rn(v, dval));
        }
        lres[i] = x;
    }
    __syncthreads();

    // ---- window compute: sg owns 8 atoms (a0 = sg*8), pg owns 2 positions ----
    int sg = t >> 3, pg = t & 7;
    int base = pg * 2;
    float acc[8][2];
    dot8p2(lres, base, (const float4*)d_t + sg * 8, acc);

    float bestv[2] = {-INFINITY, -INFINITY};
    int   besta[2] = {0, 0};
#pragma unroll
    for (int aa = 0; aa < 8; ++aa)
#pragma unroll
        for (int j = 0; j < 2; ++j)
            if (acc[aa][j] > bestv[j]) { bestv[j] = acc[aa][j]; besta[j] = sg * 8 + aa; }
#pragma unroll
    for (int j = 0; j < 2; ++j)
        kk[sg * 17 + base + j] = packkey(bestv[j], besta[j], qstart + base + j);
    __syncthreads();
    for (int off = 16; off; off >>= 1) {
        if (sg < off) {
#pragma unroll
            for (int j = 0; j < 2; ++j) {
                unsigned long long o = kk[(sg + off) * 17 + base + j];
                if (o > kk[sg * 17 + base + j]) kk[sg * 17 + base + j] = o;
            }
        }
        __syncthreads();
    }
    // exclusive store of the block's 16 positions (row 0 of kk)
    if (t < 16) {
        int q = qstart + t;
        if (q < w1) mkey[c * NLEN + q] = kk[t];
    }

    // ---- scan duty + combined block max -> stepkey[k+1] ----
    unsigned long long myk = 0ull;
    {
        const unsigned long long* mk = mkey + c * NLEN;
        int q0 = r * 512;
#pragma unroll
        for (int i2 = 0; i2 < 2; ++i2) {
            int q = q0 + i2 * 256 + t;
            if (q < w0 || q >= w1) {
                unsigned long long z = mk[q];
                if (z > myk) myk = z;
            }
        }
    }
    if (t < 16) {
        int q = qstart + t;
        if (q < w1) {
            unsigned long long z = kk[t];
            if (z > myk) myk = z;
        }
    }
    kred[t] = myk;
    __syncthreads();
    for (int off = 128; off; off >>= 1) {
        if (t < off) { if (kred[t + off] > kred[t]) kred[t] = kred[t + off]; }
        __syncthreads();
    }
    if (t == 0) atomicMax(&stepkey[(k + 1) * NCHAN + c], kred[0]);
}

// ---------- final loss from stepkey (one block, 256 threads) ----------
__global__ __launch_bounds__(256) void loss_kernel(const unsigned long long* __restrict__ stepkey,
                                                   float* __restrict__ out) {
    int t = threadIdx.x;
    __shared__ int   lsa[NSEL], lsp[NSEL];
    __shared__ float lsv[NSEL];
    __shared__ double red[256];
    __shared__ double smx;

    if (t < NSEL) {
        int c = t >> 4, k = t & 15;            // sel index = c*NSTEPS + k
        unsigned long long key = stepkey[k * NCHAN + c];
        lsa[t] = 255 - (int)((key >> 15) & 255);
        lsp[t] = (NLEN - 1) - (int)(key & 32767);
        lsv[t] = unord32((unsigned int)(key >> 23));
    }
    __syncthreads();

    int myc = (t < NSEL) ? (t >> 4) : -1;
    int mya = (t < NSEL) ? lsa[t] : -1;
    int myp = (t < NSEL) ? lsp[t] : -1;

    // per-(c,a,p) dedup
    int fullowner = t;
    double fullsum = 0.0;
    if (t < NSEL) {
        for (int j = 0; j < NSEL; ++j) {
            if ((j >> 4) == myc && lsa[j] == mya && lsp[j] == myp) {
                if (j < fullowner) fullowner = j;
                fullsum += (double)lsv[j];
            }
        }
    }
    red[t] = (t < NSEL && fullowner == t) ? fullsum : 0.0;
    __syncthreads();
    for (int off = 128; off; off >>= 1) {
        if (t < off) red[t] = fmax(red[t], red[t + off]);
        __syncthreads();
    }
    if (t == 0) smx = red[0];
    __syncthreads();
    double mx = smx;

    // per-(b,a,p) group across r/t halves
    int gowner = t;
    double rv = 0.0, tv = 0.0;
    if (t < NSEL) {
        int myb = myc & 3;
        for (int j = 0; j < NSEL; ++j) {
            int jc = j >> 4;
            if ((jc & 3) == myb && lsa[j] == mya && lsp[j] == myp) {
                if (j < gowner) gowner = j;
                if (jc < 4) rv += (double)lsv[j]; else tv += (double)lsv[j];
            }
        }
    }

    const double EPS = 1e-12;
    double bg_term = -log1p(-EPS);

    double extra = 0.0;
    if (t < NSEL && gowner == t) {
        double r = rv / mx, tt = tv / mx;
        double rc = r;
        if (rc < EPS) rc = EPS;
        if (rc > 1.0) rc = 1.0;
        double lr = log(rc);  if (lr < -100.0) lr = -100.0;
        double l1 = (rc >= 1.0) ? -100.0 : log1p(-rc);
        if (l1 < -100.0) l1 = -100.0;
        double term = -(tt * lr + (1.0 - tt) * l1);
        extra = term - bg_term;
    }

    red[t] = extra;
    __syncthreads();
    for (int off = 128; off; off >>= 1) {
        if (t < off) red[t] += red[t + off];
        __syncthreads();
    }
    if (t == 0) {
        const double count = 33554432.0;  // 4 * 256 * 32768
        double total = count * bg_term + red[0];
        out[0] = (float)(total / count);
    }
}

// ---------- launch ----------
extern "C" void kernel_launch(void* const* d_in, const int* in_sizes, int n_in,
                              void* d_out, int out_size, void* d_ws, size_t ws_size,
                              hipStream_t stream) {
    const float* recon  = (const float*)d_in[0];
    const float* target = (const float*)d_in[1];
    const float* d      = (const float*)d_in[2];
    char* ws = (char*)d_ws;
    float* d_t                    = (float*)(ws);                        // 512 KB
    float* res0                   = (float*)(ws + 524288);               // 1 MB (must follow d_t: dot8p over-read)
    float* res1                   = (float*)(ws + 1572864);              // 1 MB
    unsigned long long* mkey      = (unsigned long long*)(ws + 2621440); // 2 MB
    unsigned long long* stepkey   = (unsigned long long*)(ws + 4718592); // 1 KB
    float* out = (float*)d_out;

    hipLaunchKernelGGL(prep_kernel, dim3(NATOMS + 33), dim3(256), 0, stream,
                       recon, target, d, d_t, res0, res1, mkey, stepkey);
    hipLaunchKernelGGL(init_conv, dim3(32, NCHAN, 8), dim3(256), 0, stream,
                       res0, d_t, mkey, stepkey);
    for (int k = 0; k < NSTEPS - 1; ++k) {
        float* cur  = (k & 1) ? res1 : res0;
        float* next = (k & 1) ? res0 : res1;
        hipLaunchKernelGGL(step_kernel, dim3(512), dim3(256), 0, stream,
                           cur, next, d_t, mkey, stepkey, k);
    }
    hipLaunchKernelGGL(loss_kernel, dim3(1), dim3(256), 0, stream,
                       stepkey, out);
}

// Round 9
// 1013.548 us; speedup vs baseline: 1.5974x; 1.5974x over previous
//
#include <hip/hip_runtime.h>
#include <math.h>

#define NLEN   32768
#define NATOMS 256
#define ATOM_S 512
#define NSTEPS 16
#define NCHAN  8   // 2 signals x 4 batches
#define NSEL   (NCHAN * NSTEPS)   // 128

typedef unsigned short ushort_t;
typedef __attribute__((ext_vector_type(8))) short bf16x8;
typedef __attribute__((ext_vector_type(16))) float f32x16;
#define MFMA32 __builtin_amdgcn_mfma_f32_32x32x16_bf16

// ---------- packed ordered key helpers ----------
__device__ __forceinline__ unsigned int ord32(float x) {
    unsigned int u = __float_as_uint(x);
    return (u & 0x80000000u) ? ~u : (u | 0x80000000u);
}
__device__ __forceinline__ float unord32(unsigned int o) {
    unsigned int u = (o & 0x80000000u) ? (o & 0x7FFFFFFFu) : ~o;
    return __uint_as_float(u);
}
// bigger key = bigger v, then smaller atom, then smaller position
__device__ __forceinline__ unsigned long long packkey(float v, int a, int q) {
    return ((unsigned long long)ord32(v) << 23)
         | ((unsigned long long)((255 - a) & 255) << 15)
         | (unsigned long long)((NLEN - 1 - q) & 32767);
}

// ---------- bf16 split helpers (RNE) ----------
__device__ __forceinline__ ushort_t f2bf(float x) {
    unsigned int u = __float_as_uint(x);
    unsigned int r = u + 0x7FFFu + ((u >> 16) & 1u);
    return (ushort_t)(r >> 16);
}
__device__ __forceinline__ float bf2f(ushort_t b) {
    return __uint_as_float(((unsigned int)b) << 16);
}

// ---------- prep: normalize dict (fp32 transposed + bf16 triple split), init buffers ----------
__global__ void prep_kernel(const float* __restrict__ recon,
                            const float* __restrict__ target,
                            const float* __restrict__ d,
                            float* __restrict__ d_t,
                            ushort_t* __restrict__ d1g,
                            ushort_t* __restrict__ d2g,
                            ushort_t* __restrict__ d3g,
                            float* __restrict__ res0,
                            float* __restrict__ res1,
                            unsigned long long* __restrict__ mkey,
                            unsigned long long* __restrict__ stepkey) {
    int b = blockIdx.x, t = threadIdx.x;
    if (b < NATOMS) {
        __shared__ float red[256];
        float x0 = d[b * ATOM_S + t];
        float x1 = d[b * ATOM_S + 256 + t];
        red[t] = x0 * x0 + x1 * x1;
        __syncthreads();
        for (int off = 128; off; off >>= 1) {
            if (t < off) red[t] += red[t + off];
            __syncthreads();
        }
        float denom = sqrtf(red[0]) + 1e-8f;
        float xn0 = x0 / denom, xn1 = x1 / denom;
        int s0 = t, s1 = t + 256;
        d_t[((s0 >> 2) * NATOMS + b) * 4 + (s0 & 3)] = xn0;
        d_t[((s1 >> 2) * NATOMS + b) * 4 + (s1 & 3)] = xn1;
        // bf16 triple split, row-major [a][s]
        {
            ushort_t a1 = f2bf(xn0); float r1 = xn0 - bf2f(a1);
            ushort_t a2 = f2bf(r1);  float r2 = r1 - bf2f(a2);
            ushort_t a3 = f2bf(r2);
            d1g[b * ATOM_S + s0] = a1; d2g[b * ATOM_S + s0] = a2; d3g[b * ATOM_S + s0] = a3;
        }
        {
            ushort_t a1 = f2bf(xn1); float r1 = xn1 - bf2f(a1);
            ushort_t a2 = f2bf(r1);  float r2 = r1 - bf2f(a2);
            ushort_t a3 = f2bf(r2);
            d1g[b * ATOM_S + s1] = a1; d2g[b * ATOM_S + s1] = a2; d3g[b * ATOM_S + s1] = a3;
        }
    } else if (b < NATOMS + 32) {
        int blk = b - NATOMS;
        for (int i = 0; i < 32; ++i) {
            int idx = blk * 8192 + i * 256 + t;     // 0 .. 262143
            int c = idx >> 15, q = idx & (NLEN - 1);
            float x = (c < 4) ? recon[c * NLEN + q] : target[(c - 4) * NLEN + q];
            res0[idx] = x;
            res1[idx] = x;
            mkey[idx] = 0ull;
        }
    } else {
        if (t < NSEL) stepkey[t] = 0ull;
    }
}

// ---------- MFMA fragment loaders ----------
__device__ __forceinline__ bf16x8 ldfragA(const ushort_t* __restrict__ dg, int off) {
    union { uint4 u4; bf16x8 v; } f;
    f.u4 = *(const uint4*)(dg + off);       // 16B-aligned by construction
    return f.v;
}
// parity-dual LDS arrays: arrA[i] = s[i], arrB[i] = s[i+1]; 8 bf16 from index s0
__device__ __forceinline__ bf16x8 ldfragB(const ushort_t* arrA, const ushort_t* arrB, int s0) {
    const unsigned int* p = (const unsigned int*)((s0 & 1) ? arrB : arrA);
    int dw = s0 >> 1;
    union { unsigned int u[4]; bf16x8 v; } f;
    f.u[0] = p[dw]; f.u[1] = p[dw + 1]; f.u[2] = p[dw + 2]; f.u[3] = p[dw + 3];
    return f.v;
}

__device__ __forceinline__ f32x16 six_mfma(bf16x8 A1, bf16x8 A2, bf16x8 A3,
                                           const ushort_t* sA1, const ushort_t* sB1,
                                           const ushort_t* sA2, const ushort_t* sB2,
                                           const ushort_t* sA3, const ushort_t* sB3,
                                           int sq, f32x16 acc) {
    bf16x8 B1 = ldfragB(sA1, sB1, sq);
    bf16x8 B2 = ldfragB(sA2, sB2, sq);
    bf16x8 B3 = ldfragB(sA3, sB3, sq);
    acc = MFMA32(A1, B1, acc, 0, 0, 0);
    acc = MFMA32(A1, B2, acc, 0, 0, 0);
    acc = MFMA32(A2, B1, acc, 0, 0, 0);
    acc = MFMA32(A2, B2, acc, 0, 0, 0);
    acc = MFMA32(A1, B3, acc, 0, 0, 0);
    acc = MFMA32(A3, B1, acc, 0, 0, 0);
    return acc;
}

// C/D mapping (m74/m101): col=lane&31, row=(reg&3)+8*(reg>>2)+4*(lane>>5)
__device__ __forceinline__ void epi_tile(const f32x16& acc, int nt, int a0w, int l,
                                         int qt, int wid, unsigned long long* warr) {
    unsigned long long key = 0ull;
#pragma unroll
    for (int reg = 0; reg < 16; ++reg) {
        float vv = acc[reg];
        int atom = a0w + (reg & 3) + 8 * (reg >> 2) + 4 * (l >> 5);
        unsigned long long kk2 = packkey(vv, atom, qt + nt * 32 + (l & 31));
        if (kk2 > key) key = kk2;
    }
    unsigned long long o = __shfl_xor(key, 32);
    if (o > key) key = o;
    if (l < 32) warr[wid * 128 + nt * 32 + (l & 31)] = key;
}

// ---------- initial full correlation via bf16-split MFMA ----------
// grid (256 pos-tiles of 128, 8 channels, 2 atom-halves of 128), 256 threads = 4 waves.
// wave w: atoms [half*128 + w*32, +32) x positions [qt, qt+128) as 4 N-tiles of 32.
__global__ __launch_bounds__(256) void init_mfma(const float* __restrict__ res,
                                                 const ushort_t* __restrict__ d1g,
                                                 const ushort_t* __restrict__ d2g,
                                                 const ushort_t* __restrict__ d3g,
                                                 unsigned long long* __restrict__ mkey,
                                                 unsigned long long* __restrict__ stepkey) {
    __shared__ __align__(16) ushort_t sA1[656], sB1[656], sA2[656], sB2[656], sA3[656], sB3[656];
    __shared__ unsigned long long warr[512];
    __shared__ unsigned long long kred[128];
    int t = threadIdx.x;
    int qt = blockIdx.x * 128;
    int c  = blockIdx.y;
    int half = blockIdx.z;

    // stage residual window, split to bf16 triples (parity-dual copies)
    const float* rc_ = res + c * NLEN;
    for (int i = t; i < 656; i += 256) {
        int g = qt + i;
        float x = (g < NLEN) ? rc_[g] : 0.0f;
        ushort_t b1 = f2bf(x);  float x1 = x - bf2f(b1);
        ushort_t b2 = f2bf(x1); float x2 = x1 - bf2f(b2);
        ushort_t b3 = f2bf(x2);
        sA1[i] = b1; sA2[i] = b2; sA3[i] = b3;
        if (i > 0) { sB1[i - 1] = b1; sB2[i - 1] = b2; sB3[i - 1] = b3; }
    }
    __syncthreads();

    int wid = t >> 6, l = t & 63;
    int a0w = half * 128 + wid * 32;
    int lk = (l >> 5) * 8;     // k-offset within fragment
    int lr = l & 31;           // A-row (atom) / B-col (position) lane index

    f32x16 acc0 = (f32x16)(0.0f), acc1 = (f32x16)(0.0f);
    f32x16 acc2 = (f32x16)(0.0f), acc3 = (f32x16)(0.0f);

    int abase = (a0w + lr) * ATOM_S + lk;   // bf16 element index; +16 per k-step
#pragma unroll 1
    for (int ks = 0; ks < 32; ++ks) {
        bf16x8 A1 = ldfragA(d1g, abase);
        bf16x8 A2 = ldfragA(d2g, abase);
        bf16x8 A3 = ldfragA(d3g, abase);
        int s0 = ks * 16 + lr + lk;
        acc0 = six_mfma(A1, A2, A3, sA1, sB1, sA2, sB2, sA3, sB3, s0,       acc0);
        acc1 = six_mfma(A1, A2, A3, sA1, sB1, sA2, sB2, sA3, sB3, s0 + 32,  acc1);
        acc2 = six_mfma(A1, A2, A3, sA1, sB1, sA2, sB2, sA3, sB3, s0 + 64,  acc2);
        acc3 = six_mfma(A1, A2, A3, sA1, sB1, sA2, sB2, sA3, sB3, s0 + 96,  acc3);
        abase += 16;
    }

    epi_tile(acc0, 0, a0w, l, qt, wid, warr);
    epi_tile(acc1, 1, a0w, l, qt, wid, warr);
    epi_tile(acc2, 2, a0w, l, qt, wid, warr);
    epi_tile(acc3, 3, a0w, l, qt, wid, warr);
    __syncthreads();

    if (t < 128) {
        unsigned long long f = warr[t];
        if (warr[128 + t] > f) f = warr[128 + t];
        if (warr[256 + t] > f) f = warr[256 + t];
        if (warr[384 + t] > f) f = warr[384 + t];
        atomicMax(&mkey[c * NLEN + qt + t], f);
        kred[t] = f;
    }
    __syncthreads();
    for (int off = 64; off; off >>= 1) {
        if (t < off) { if (kred[t + off] > kred[t]) kred[t] = kred[t + off]; }
        __syncthreads();
    }
    if (t == 0) atomicMax(&stepkey[c], kred[0]);
}

// ---------- fp32 VALU pieces for the steps (R7 versions, bit-exact path) ----------
__device__ __forceinline__ void fma16(float acc[4], float4 dv,
                                      const float4& rc, const float4& rn) {
    acc[0] = fmaf(rc.x, dv.x, acc[0]); acc[0] = fmaf(rc.y, dv.y, acc[0]);
    acc[0] = fmaf(rc.z, dv.z, acc[0]); acc[0] = fmaf(rc.w, dv.w, acc[0]);
    acc[1] = fmaf(rc.y, dv.x, acc[1]); acc[1] = fmaf(rc.z, dv.y, acc[1]);
    acc[1] = fmaf(rc.w, dv.z, acc[1]); acc[1] = fmaf(rn.x, dv.w, acc[1]);
    acc[2] = fmaf(rc.z, dv.x, acc[2]); acc[2] = fmaf(rc.w, dv.y, acc[2]);
    acc[2] = fmaf(rn.x, dv.z, acc[2]); acc[2] = fmaf(rn.y, dv.w, acc[2]);
    acc[3] = fmaf(rc.w, dv.x, acc[3]); acc[3] = fmaf(rn.x, dv.y, acc[3]);
    acc[3] = fmaf(rn.y, dv.z, acc[3]); acc[3] = fmaf(rn.z, dv.w, acc[3]);
}

// 8-atom x 4-pos dot with 2-deep d_t register prefetch.
// NOTE: prefetches up to 255 float4 past d_t's end (lands in res0, unused).
__device__ __forceinline__ void dot8p(const float* __restrict__ lres, int base,
                                      const float4* __restrict__ dt0,
                                      float acc[8][4]) {
#pragma unroll
    for (int aa = 0; aa < 8; ++aa)
#pragma unroll
        for (int j = 0; j < 4; ++j) acc[aa][j] = 0.0f;
    float4 dva[8], dvb[8];
#pragma unroll
    for (int aa = 0; aa < 8; ++aa) dva[aa] = dt0[aa];
    float4 rc = *(const float4*)&lres[base];
    const float4* dtp = dt0;
#pragma unroll 1
    for (int s4 = 0; s4 < ATOM_S / 4; s4 += 2) {
        float4 rn = *(const float4*)&lres[base + s4 * 4 + 4];
#pragma unroll
        for (int aa = 0; aa < 8; ++aa) dvb[aa] = dtp[NATOMS + aa];
#pragma unroll
        for (int aa = 0; aa < 8; ++aa) fma16(acc[aa], dva[aa], rc, rn);
        float4 rn2 = *(const float4*)&lres[base + s4 * 4 + 8];
#pragma unroll
        for (int aa = 0; aa < 8; ++aa) dva[aa] = dtp[2 * NATOMS + aa];
#pragma unroll
        for (int aa = 0; aa < 8; ++aa) fma16(acc[aa], dvb[aa], rn, rn2);
        dtp += 2 * NATOMS;
        rc = rn2;
    }
}

// ---------- per-step kernel (R7 version: 256 blocks x 256 threads) ----------
__global__ __launch_bounds__(256) void step_kernel(const float* __restrict__ buf_cur,
                                                   float* __restrict__ buf_next,
                                                   const float* __restrict__ d_t,
                                                   unsigned long long* __restrict__ mkey,
                                                   unsigned long long* __restrict__ stepkey,
                                                   int k) {
    int b = blockIdx.x, t = threadIdx.x;
    int c = b >> 5, r = b & 31;
    __shared__ __align__(16) float lres[544 + 16];
    __shared__ unsigned long long kk[32 * 33];
    __shared__ unsigned long long kred[256];

    unsigned long long key = stepkey[k * NCHAN + c];
    int a = 255 - (int)((key >> 15) & 255);
    int p = (NLEN - 1) - (int)(key & 32767);
    float v = unord32((unsigned int)(key >> 23));
    int w0 = max(0, p - (ATOM_S - 1));
    int w1 = min(NLEN, p + ATOM_S);
    int qstart = w0 + r * 32;

    if (r == 0) {
        float* bn = buf_next + c * NLEN;
        int s0 = (k > 0) ? (k - 1) : 0;
        for (int s = s0; s <= k; ++s) {
            unsigned long long ks = stepkey[s * NCHAN + c];
            int as = 255 - (int)((ks >> 15) & 255);
            int ps = (NLEN - 1) - (int)(ks & 32767);
            float vs = unord32((unsigned int)(ks >> 23));
            for (int i = t; i < ATOM_S; i += 256) {
                int q = ps + i;
                if (q < NLEN) {
                    float dval = d_t[((i >> 2) * NATOMS + as) * 4 + (i & 3)];
                    bn[q] = __fsub_rn(bn[q], __fmul_rn(vs, dval));
                }
            }
            __syncthreads();
        }
    }

    const float* rcur = buf_cur + c * NLEN;
    for (int i = t; i < 544; i += 256) {
        int g = qstart + i;
        float x = (g < NLEN) ? rcur[g] : 0.0f;
        int s = g - p;
        if (s >= 0 && s < ATOM_S && g < NLEN) {
            float dval = d_t[((s >> 2) * NATOMS + a) * 4 + (s & 3)];
            x = __fsub_rn(x, __fmul_rn(v, dval));
        }
        lres[i] = x;
    }
    __syncthreads();

    int sg = t >> 3, pg = t & 7;
    int base = pg * 4;
    float acc[8][4];
    dot8p(lres, base, (const float4*)d_t + sg * 8, acc);

    float bestv[4] = {-INFINITY, -INFINITY, -INFINITY, -INFINITY};
    int   besta[4] = {0, 0, 0, 0};
#pragma unroll
    for (int aa = 0; aa < 8; ++aa)
#pragma unroll
        for (int j = 0; j < 4; ++j)
            if (acc[aa][j] > bestv[j]) { bestv[j] = acc[aa][j]; besta[j] = sg * 8 + aa; }
#pragma unroll
    for (int j = 0; j < 4; ++j)
        kk[sg * 33 + base + j] = packkey(bestv[j], besta[j], qstart + base + j);
    __syncthreads();
    for (int off = 16; off; off >>= 1) {
        if (sg < off) {
#pragma unroll
            for (int j = 0; j < 4; ++j) {
                unsigned long long o = kk[(sg + off) * 33 + base + j];
                if (o > kk[sg * 33 + base + j]) kk[sg * 33 + base + j] = o;
            }
        }
        __syncthreads();
    }
    if (t < 8) {
        unsigned long long* mk = mkey + c * NLEN;
#pragma unroll
        for (int j = 0; j < 4; ++j) {
            int q = qstart + t * 4 + j;
            if (q < w1) mk[q] = kk[t * 4 + j];
        }
    }

    unsigned long long myk = 0ull;
    {
        const unsigned long long* mk = mkey + c * NLEN;
        int q0 = r * 1024;
#pragma unroll
        for (int i2 = 0; i2 < 4; ++i2) {
            int q = q0 + i2 * 256 + t;
            if (q < w0 || q >= w1) {
                unsigned long long z = mk[q];
                if (z > myk) myk = z;
            }
        }
    }
    if (t < 32) {
        int q = qstart + t;
        if (q < w1) {
            unsigned long long z = kk[t];
            if (z > myk) myk = z;
        }
    }
    kred[t] = myk;
    __syncthreads();
    for (int off = 128; off; off >>= 1) {
        if (t < off) { if (kred[t + off] > kred[t]) kred[t] = kred[t + off]; }
        __syncthreads();
    }
    if (t == 0) atomicMax(&stepkey[(k + 1) * NCHAN + c], kred[0]);
}

// ---------- final loss from stepkey (one block, 256 threads) ----------
__global__ __launch_bounds__(256) void loss_kernel(const unsigned long long* __restrict__ stepkey,
                                                   float* __restrict__ out) {
    int t = threadIdx.x;
    __shared__ int   lsa[NSEL], lsp[NSEL];
    __shared__ float lsv[NSEL];
    __shared__ double red[256];
    __shared__ double smx;

    if (t < NSEL) {
        int c = t >> 4, k = t & 15;
        unsigned long long key = stepkey[k * NCHAN + c];
        lsa[t] = 255 - (int)((key >> 15) & 255);
        lsp[t] = (NLEN - 1) - (int)(key & 32767);
        lsv[t] = unord32((unsigned int)(key >> 23));
    }
    __syncthreads();

    int myc = (t < NSEL) ? (t >> 4) : -1;
    int mya = (t < NSEL) ? lsa[t] : -1;
    int myp = (t < NSEL) ? lsp[t] : -1;

    int fullowner = t;
    double fullsum = 0.0;
    if (t < NSEL) {
        for (int j = 0; j < NSEL; ++j) {
            if ((j >> 4) == myc && lsa[j] == mya && lsp[j] == myp) {
                if (j < fullowner) fullowner = j;
                fullsum += (double)lsv[j];
            }
        }
    }
    red[t] = (t < NSEL && fullowner == t) ? fullsum : 0.0;
    __syncthreads();
    for (int off = 128; off; off >>= 1) {
        if (t < off) red[t] = fmax(red[t], red[t + off]);
        __syncthreads();
    }
    if (t == 0) smx = red[0];
    __syncthreads();
    double mx = smx;

    int gowner = t;
    double rv = 0.0, tv = 0.0;
    if (t < NSEL) {
        int myb = myc & 3;
        for (int j = 0; j < NSEL; ++j) {
            int jc = j >> 4;
            if ((jc & 3) == myb && lsa[j] == mya && lsp[j] == myp) {
                if (j < gowner) gowner = j;
                if (jc < 4) rv += (double)lsv[j]; else tv += (double)lsv[j];
            }
        }
    }

    const double EPS = 1e-12;
    double bg_term = -log1p(-EPS);

    double extra = 0.0;
    if (t < NSEL && gowner == t) {
        double r = rv / mx, tt = tv / mx;
        double rc = r;
        if (rc < EPS) rc = EPS;
        if (rc > 1.0) rc = 1.0;
        double lr = log(rc);  if (lr < -100.0) lr = -100.0;
        double l1 = (rc >= 1.0) ? -100.0 : log1p(-rc);
        if (l1 < -100.0) l1 = -100.0;
        double term = -(tt * lr + (1.0 - tt) * l1);
        extra = term - bg_term;
    }

    red[t] = extra;
    __syncthreads();
    for (int off = 128; off; off >>= 1) {
        if (t < off) red[t] += red[t + off];
        __syncthreads();
    }
    if (t == 0) {
        const double count = 33554432.0;  // 4 * 256 * 32768
        double total = count * bg_term + red[0];
        out[0] = (float)(total / count);
    }
}

// ---------- launch ----------
extern "C" void kernel_launch(void* const* d_in, const int* in_sizes, int n_in,
                              void* d_out, int out_size, void* d_ws, size_t ws_size,
                              hipStream_t stream) {
    const float* recon  = (const float*)d_in[0];
    const float* target = (const float*)d_in[1];
    const float* d      = (const float*)d_in[2];
    char* ws = (char*)d_ws;
    float* d_t                    = (float*)(ws);                        // 512 KB
    float* res0                   = (float*)(ws + 524288);               // 1 MB (follows d_t: dot8p over-read)
    float* res1                   = (float*)(ws + 1572864);              // 1 MB
    unsigned long long* mkey      = (unsigned long long*)(ws + 2621440); // 2 MB
    unsigned long long* stepkey   = (unsigned long long*)(ws + 4718592); // 1 KB
    ushort_t* d1g                 = (ushort_t*)(ws + 4719616);           // 256 KB
    ushort_t* d2g                 = (ushort_t*)(ws + 4981760);           // 256 KB
    ushort_t* d3g                 = (ushort_t*)(ws + 5243904);           // 256 KB
    float* out = (float*)d_out;

    hipLaunchKernelGGL(prep_kernel, dim3(NATOMS + 33), dim3(256), 0, stream,
                       recon, target, d, d_t, d1g, d2g, d3g, res0, res1, mkey, stepkey);
    hipLaunchKernelGGL(init_mfma, dim3(256, NCHAN, 2), dim3(256), 0, stream,
                       res0, d1g, d2g, d3g, mkey, stepkey);
    for (int k = 0; k < NSTEPS - 1; ++k) {
        float* cur  = (k & 1) ? res1 : res0;
        float* next = (k & 1) ? res0 : res1;
        hipLaunchKernelGGL(step_kernel, dim3(256), dim3(256), 0, stream,
                           cur, next, d_t, mkey, stepkey, k);
    }
    hipLaunchKernelGGL(loss_kernel, dim3(1), dim3(256), 0, stream,
                       stepkey, out);
}

// Round 10
// 806.233 us; speedup vs baseline: 2.0082x; 1.2571x over previous
//
#include <hip/hip_runtime.h>
#include <math.h>

#define NLEN   32768
#define NATOMS 256
#define ATOM_S 512
#define NSTEPS 16
#define NCHAN  8   // 2 signals x 4 batches
#define NSEL   (NCHAN * NSTEPS)   // 128

typedef unsigned short ushort_t;
typedef __attribute__((ext_vector_type(8))) short bf16x8;
typedef __attribute__((ext_vector_type(16))) float f32x16;
#define MFMA32 __builtin_amdgcn_mfma_f32_32x32x16_bf16

// ---------- packed ordered key helpers ----------
__device__ __forceinline__ unsigned int ord32(float x) {
    unsigned int u = __float_as_uint(x);
    return (u & 0x80000000u) ? ~u : (u | 0x80000000u);
}
__device__ __forceinline__ float unord32(unsigned int o) {
    unsigned int u = (o & 0x80000000u) ? (o & 0x7FFFFFFFu) : ~o;
    return __uint_as_float(u);
}
// bigger key = bigger v, then smaller atom, then smaller position
__device__ __forceinline__ unsigned long long packkey(float v, int a, int q) {
    return ((unsigned long long)ord32(v) << 23)
         | ((unsigned long long)((255 - a) & 255) << 15)
         | (unsigned long long)((NLEN - 1 - q) & 32767);
}

// ---------- bf16 split helpers (RNE) ----------
__device__ __forceinline__ ushort_t f2bf(float x) {
    unsigned int u = __float_as_uint(x);
    unsigned int r = u + 0x7FFFu + ((u >> 16) & 1u);
    return (ushort_t)(r >> 16);
}
__device__ __forceinline__ float bf2f(ushort_t b) {
    return __uint_as_float(((unsigned int)b) << 16);
}

// ---------- prep: normalize dict (fp32 transposed + bf16 triple split), init buffers ----------
__global__ void prep_kernel(const float* __restrict__ recon,
                            const float* __restrict__ target,
                            const float* __restrict__ d,
                            float* __restrict__ d_t,
                            ushort_t* __restrict__ d1g,
                            ushort_t* __restrict__ d2g,
                            ushort_t* __restrict__ d3g,
                            float* __restrict__ res0,
                            float* __restrict__ res1,
                            unsigned long long* __restrict__ mkey,
                            unsigned long long* __restrict__ stepkey) {
    int b = blockIdx.x, t = threadIdx.x;
    if (b < NATOMS) {
        __shared__ float red[256];
        float x0 = d[b * ATOM_S + t];
        float x1 = d[b * ATOM_S + 256 + t];
        red[t] = x0 * x0 + x1 * x1;
        __syncthreads();
        for (int off = 128; off; off >>= 1) {
            if (t < off) red[t] += red[t + off];
            __syncthreads();
        }
        float denom = sqrtf(red[0]) + 1e-8f;
        float xn0 = x0 / denom, xn1 = x1 / denom;
        int s0 = t, s1 = t + 256;
        d_t[((s0 >> 2) * NATOMS + b) * 4 + (s0 & 3)] = xn0;
        d_t[((s1 >> 2) * NATOMS + b) * 4 + (s1 & 3)] = xn1;
        {
            ushort_t a1 = f2bf(xn0); float r1 = xn0 - bf2f(a1);
            ushort_t a2 = f2bf(r1);  float r2 = r1 - bf2f(a2);
            ushort_t a3 = f2bf(r2);
            d1g[b * ATOM_S + s0] = a1; d2g[b * ATOM_S + s0] = a2; d3g[b * ATOM_S + s0] = a3;
        }
        {
            ushort_t a1 = f2bf(xn1); float r1 = xn1 - bf2f(a1);
            ushort_t a2 = f2bf(r1);  float r2 = r1 - bf2f(a2);
            ushort_t a3 = f2bf(r2);
            d1g[b * ATOM_S + s1] = a1; d2g[b * ATOM_S + s1] = a2; d3g[b * ATOM_S + s1] = a3;
        }
    } else if (b < NATOMS + 32) {
        int blk = b - NATOMS;
        for (int i = 0; i < 32; ++i) {
            int idx = blk * 8192 + i * 256 + t;     // 0 .. 262143
            int c = idx >> 15, q = idx & (NLEN - 1);
            float x = (c < 4) ? recon[c * NLEN + q] : target[(c - 4) * NLEN + q];
            res0[idx] = x;
            res1[idx] = x;
            mkey[idx] = 0ull;
        }
    } else {
        if (t < NSEL) stepkey[t] = 0ull;
    }
}

// ---------- MFMA fragment loaders ----------
__device__ __forceinline__ bf16x8 ldfragA(const ushort_t* __restrict__ dg, int off) {
    union { uint4 u4; bf16x8 v; } f;
    f.u4 = *(const uint4*)(dg + off);       // 16B-aligned by construction
    return f.v;
}
// parity-dual LDS arrays: arrA[i] = s[i], arrB[i] = s[i+1]; 8 bf16 from index s0
__device__ __forceinline__ bf16x8 ldfragB(const ushort_t* arrA, const ushort_t* arrB, int s0) {
    const unsigned int* p = (const unsigned int*)((s0 & 1) ? arrB : arrA);
    int dw = s0 >> 1;
    union { unsigned int u[4]; bf16x8 v; } f;
    f.u[0] = p[dw]; f.u[1] = p[dw + 1]; f.u[2] = p[dw + 2]; f.u[3] = p[dw + 3];
    return f.v;
}

// ---------- stage one fp32 value as bf16 triple into parity-dual LDS ----------
__device__ __forceinline__ void stage_split(float x, int i,
                                            ushort_t* sA1, ushort_t* sB1,
                                            ushort_t* sA2, ushort_t* sB2,
                                            ushort_t* sA3, ushort_t* sB3) {
    ushort_t b1 = f2bf(x);  float x1 = x - bf2f(b1);
    ushort_t b2 = f2bf(x1); float x2 = x1 - bf2f(b2);
    ushort_t b3 = f2bf(x2);
    sA1[i] = b1; sA2[i] = b2; sA3[i] = b3;
    if (i > 0) { sB1[i - 1] = b1; sB2[i - 1] = b2; sB3[i - 1] = b3; }
}

// ---------- unified MFMA conv tile: 64 atoms x NT*32 positions per wave ----------
// Per-acc product order A1B1,A1B2,A2B1,A2B2,A1B3,A3B1, ks ascending -> bitwise
// stable regardless of NT / tile alignment. 2*NT independent chains per sweep.
template<int NT>
__device__ __forceinline__ void conv_tile(const ushort_t* __restrict__ d1g,
                                          const ushort_t* __restrict__ d2g,
                                          const ushort_t* __restrict__ d3g,
                                          const ushort_t* sA1, const ushort_t* sB1,
                                          const ushort_t* sA2, const ushort_t* sB2,
                                          const ushort_t* sA3, const ushort_t* sB3,
                                          int a0w, int lr, int lk,
                                          f32x16 acc[2][NT]) {
#pragma unroll
    for (int at = 0; at < 2; ++at)
#pragma unroll
        for (int nt = 0; nt < NT; ++nt) acc[at][nt] = (f32x16)(0.0f);

    int ab0 = (a0w + lr) * ATOM_S + lk;
    int ab1 = (a0w + 32 + lr) * ATOM_S + lk;
    bf16x8 A1[2], A2[2], A3[2];
    A1[0] = ldfragA(d1g, ab0); A2[0] = ldfragA(d2g, ab0); A3[0] = ldfragA(d3g, ab0);
    A1[1] = ldfragA(d1g, ab1); A2[1] = ldfragA(d2g, ab1); A3[1] = ldfragA(d3g, ab1);

#pragma unroll 1
    for (int ks = 0; ks < 32; ++ks) {
        int s0 = ks * 16 + lr + lk;
        bf16x8 B1[NT], B2[NT], B3[NT];
#pragma unroll
        for (int nt = 0; nt < NT; ++nt) {
            B1[nt] = ldfragB(sA1, sB1, s0 + nt * 32);
            B2[nt] = ldfragB(sA2, sB2, s0 + nt * 32);
            B3[nt] = ldfragB(sA3, sB3, s0 + nt * 32);
        }
        bf16x8 nA1[2], nA2[2], nA3[2];
        if (ks < 31) {
            nA1[0] = ldfragA(d1g, ab0 + 16); nA2[0] = ldfragA(d2g, ab0 + 16); nA3[0] = ldfragA(d3g, ab0 + 16);
            nA1[1] = ldfragA(d1g, ab1 + 16); nA2[1] = ldfragA(d2g, ab1 + 16); nA3[1] = ldfragA(d3g, ab1 + 16);
        }
#pragma unroll
        for (int at = 0; at < 2; ++at)
#pragma unroll
            for (int nt = 0; nt < NT; ++nt)
                acc[at][nt] = MFMA32(A1[at], B1[nt], acc[at][nt], 0, 0, 0);
#pragma unroll
        for (int at = 0; at < 2; ++at)
#pragma unroll
            for (int nt = 0; nt < NT; ++nt)
                acc[at][nt] = MFMA32(A1[at], B2[nt], acc[at][nt], 0, 0, 0);
#pragma unroll
        for (int at = 0; at < 2; ++at)
#pragma unroll
            for (int nt = 0; nt < NT; ++nt)
                acc[at][nt] = MFMA32(A2[at], B1[nt], acc[at][nt], 0, 0, 0);
#pragma unroll
        for (int at = 0; at < 2; ++at)
#pragma unroll
            for (int nt = 0; nt < NT; ++nt)
                acc[at][nt] = MFMA32(A2[at], B2[nt], acc[at][nt], 0, 0, 0);
#pragma unroll
        for (int at = 0; at < 2; ++at)
#pragma unroll
            for (int nt = 0; nt < NT; ++nt)
                acc[at][nt] = MFMA32(A1[at], B3[nt], acc[at][nt], 0, 0, 0);
#pragma unroll
        for (int at = 0; at < 2; ++at)
#pragma unroll
            for (int nt = 0; nt < NT; ++nt)
                acc[at][nt] = MFMA32(A3[at], B1[nt], acc[at][nt], 0, 0, 0);
        if (ks < 31) {
            A1[0] = nA1[0]; A2[0] = nA2[0]; A3[0] = nA3[0];
            A1[1] = nA1[1]; A2[1] = nA2[1]; A3[1] = nA3[1];
            ab0 += 16; ab1 += 16;
        }
    }
}

// C/D mapping (m74/m101): col=lane&31, row=(reg&3)+8*(reg>>2)+4*(lane>>5)
template<int NT>
__device__ __forceinline__ void epi_keys(const f32x16 acc[2][NT], int a0w, int l,
                                         int qt, int wid, unsigned long long* warr) {
#pragma unroll
    for (int nt = 0; nt < NT; ++nt) {
        unsigned long long key = 0ull;
#pragma unroll
        for (int at = 0; at < 2; ++at)
#pragma unroll
            for (int reg = 0; reg < 16; ++reg) {
                float vv = acc[at][nt][reg];
                int atom = a0w + at * 32 + (reg & 3) + 8 * (reg >> 2) + 4 * (l >> 5);
                unsigned long long kk2 = packkey(vv, atom, qt + nt * 32 + (l & 31));
                if (kk2 > key) key = kk2;
            }
        unsigned long long o = __shfl_xor(key, 32);
        if (o > key) key = o;
        if (l < 32) warr[wid * (NT * 32) + nt * 32 + l] = key;
    }
}

// ---------- initial full correlation via bf16-split MFMA ----------
// grid (256 pos-tiles of 128, 8 channels), 256 threads = 4 waves.
// wave w: atoms [w*64, +64) x positions [qt, qt+128) as 2 A-tiles x 4 N-tiles.
__global__ __launch_bounds__(256) void init_mfma(const float* __restrict__ res,
                                                 const ushort_t* __restrict__ d1g,
                                                 const ushort_t* __restrict__ d2g,
                                                 const ushort_t* __restrict__ d3g,
                                                 unsigned long long* __restrict__ mkey,
                                                 unsigned long long* __restrict__ stepkey) {
    __shared__ __align__(16) ushort_t sA1[656], sB1[656], sA2[656], sB2[656], sA3[656], sB3[656];
    __shared__ unsigned long long warr[512];
    __shared__ unsigned long long kred[128];
    int t = threadIdx.x;
    int qt = blockIdx.x * 128;
    int c  = blockIdx.y;

    const float* rc_ = res + c * NLEN;
    for (int i = t; i < 656; i += 256) {
        int g = qt + i;
        float x = (g < NLEN) ? rc_[g] : 0.0f;
        stage_split(x, i, sA1, sB1, sA2, sB2, sA3, sB3);
    }
    __syncthreads();

    int wid = t >> 6, l = t & 63;
    int a0w = wid * 64;
    int lk = (l >> 5) * 8;
    int lr = l & 31;

    f32x16 acc[2][4];
    conv_tile<4>(d1g, d2g, d3g, sA1, sB1, sA2, sB2, sA3, sB3, a0w, lr, lk, acc);
    epi_keys<4>(acc, a0w, l, qt, wid, warr);
    __syncthreads();

    if (t < 128) {
        unsigned long long f = warr[t];
        if (warr[128 + t] > f) f = warr[128 + t];
        if (warr[256 + t] > f) f = warr[256 + t];
        if (warr[384 + t] > f) f = warr[384 + t];
        atomicMax(&mkey[c * NLEN + qt + t], f);
        kred[t] = f;
    }
    __syncthreads();
    for (int off = 64; off; off >>= 1) {
        if (t < off) { if (kred[t + off] > kred[t]) kred[t] = kred[t + off]; }
        __syncthreads();
    }
    if (t == 0) atomicMax(&stepkey[c], kred[0]);
}

// ---------- per-step kernel: 384 blocks x 256 threads ----------
// b < 128 : window MFMA blocks: c = b>>4, tile = b&15, qt = w0 + tile*64.
//           own 64 positions x 256 atoms; stage buf_cur + delta_k on the fly
//           (fp32, same rounding as writer), exclusive mkey stores.
// b >= 128: scan blocks: c = sb>>5, seg = sb&31 (1024 pos) outside [w0,w1);
//           seg==0 blocks also advance buf_next from R_{k-1} to R_{k+1} (fp32 exact).
__global__ __launch_bounds__(256) void step_kernel(const float* __restrict__ buf_cur,
                                                   float* __restrict__ buf_next,
                                                   const float* __restrict__ d_t,
                                                   const ushort_t* __restrict__ d1g,
                                                   const ushort_t* __restrict__ d2g,
                                                   const ushort_t* __restrict__ d3g,
                                                   unsigned long long* __restrict__ mkey,
                                                   unsigned long long* __restrict__ stepkey,
                                                   int k) {
    int b = blockIdx.x, t = threadIdx.x;
    __shared__ __align__(16) ushort_t sA1[656], sB1[656], sA2[656], sB2[656], sA3[656], sB3[656];
    __shared__ unsigned long long warr[256];
    __shared__ unsigned long long kred[256];

    if (b < 128) {
        int c = b >> 4, tile = b & 15;
        unsigned long long key = stepkey[k * NCHAN + c];
        int a = 255 - (int)((key >> 15) & 255);
        int p = (NLEN - 1) - (int)(key & 32767);
        float v = unord32((unsigned int)(key >> 23));
        int w0 = max(0, p - (ATOM_S - 1));
        int w1 = min(NLEN, p + ATOM_S);
        int qt = w0 + tile * 64;

        const float* rcur = buf_cur + c * NLEN;
        for (int i = t; i < 656; i += 256) {
            int g = qt + i;
            float x = (g < NLEN) ? rcur[g] : 0.0f;
            int s = g - p;
            if (s >= 0 && s < ATOM_S && g < NLEN) {
                float dval = d_t[((s >> 2) * NATOMS + a) * 4 + (s & 3)];
                x = __fsub_rn(x, __fmul_rn(v, dval));
            }
            stage_split(x, i, sA1, sB1, sA2, sB2, sA3, sB3);
        }
        __syncthreads();

        int wid = t >> 6, l = t & 63;
        int a0w = wid * 64;
        int lk = (l >> 5) * 8;
        int lr = l & 31;

        f32x16 acc[2][2];
        conv_tile<2>(d1g, d2g, d3g, sA1, sB1, sA2, sB2, sA3, sB3, a0w, lr, lk, acc);
        epi_keys<2>(acc, a0w, l, qt, wid, warr);
        __syncthreads();

        unsigned long long myk = 0ull;
        if (t < 64) {
            unsigned long long f = warr[t];
            if (warr[64 + t]  > f) f = warr[64 + t];
            if (warr[128 + t] > f) f = warr[128 + t];
            if (warr[192 + t] > f) f = warr[192 + t];
            int q = qt + t;
            if (q < w1) {                 // exclusive owner: plain store
                mkey[c * NLEN + q] = f;
                myk = f;
            }
        }
        kred[t] = myk;
        __syncthreads();
        for (int off = 128; off; off >>= 1) {
            if (t < off) { if (kred[t + off] > kred[t]) kred[t] = kred[t + off]; }
            __syncthreads();
        }
        if (t == 0) atomicMax(&stepkey[(k + 1) * NCHAN + c], kred[0]);
    } else {
        int sb = b - 128;
        int c = sb >> 5, seg = sb & 31;
        unsigned long long key = stepkey[k * NCHAN + c];
        int p = (NLEN - 1) - (int)(key & 32767);
        int w0 = max(0, p - (ATOM_S - 1));
        int w1 = min(NLEN, p + ATOM_S);

        // writer duty: bring buf_next from R_{k-1} to R_{k+1} (sequential deltas)
        if (seg == 0) {
            float* bn = buf_next + c * NLEN;
            int s0 = (k > 0) ? (k - 1) : 0;
            for (int s = s0; s <= k; ++s) {
                unsigned long long ks = stepkey[s * NCHAN + c];
                int as = 255 - (int)((ks >> 15) & 255);
                int ps = (NLEN - 1) - (int)(ks & 32767);
                float vs = unord32((unsigned int)(ks >> 23));
                for (int i = t; i < ATOM_S; i += 256) {
                    int q = ps + i;
                    if (q < NLEN) {
                        float dval = d_t[((i >> 2) * NATOMS + as) * 4 + (i & 3)];
                        bn[q] = __fsub_rn(bn[q], __fmul_rn(vs, dval));
                    }
                }
                __syncthreads();
            }
        }

        // scan duty: max over mkey outside [w0,w1)
        const unsigned long long* mk = mkey + c * NLEN;
        unsigned long long myk = 0ull;
        int q0 = seg * 1024;
#pragma unroll
        for (int i = 0; i < 4; ++i) {
            int q = q0 + i * 256 + t;
            if (q < w0 || q >= w1) {
                unsigned long long z = mk[q];
                if (z > myk) myk = z;
            }
        }
        kred[t] = myk;
        __syncthreads();
        for (int off = 128; off; off >>= 1) {
            if (t < off) { if (kred[t + off] > kred[t]) kred[t] = kred[t + off]; }
            __syncthreads();
        }
        if (t == 0) atomicMax(&stepkey[(k + 1) * NCHAN + c], kred[0]);
    }
}

// ---------- final loss from stepkey (one block, 256 threads) ----------
__global__ __launch_bounds__(256) void loss_kernel(const unsigned long long* __restrict__ stepkey,
                                                   float* __restrict__ out) {
    int t = threadIdx.x;
    __shared__ int   lsa[NSEL], lsp[NSEL];
    __shared__ float lsv[NSEL];
    __shared__ double red[256];
    __shared__ double smx;

    if (t < NSEL) {
        int c = t >> 4, k = t & 15;
        unsigned long long key = stepkey[k * NCHAN + c];
        lsa[t] = 255 - (int)((key >> 15) & 255);
        lsp[t] = (NLEN - 1) - (int)(key & 32767);
        lsv[t] = unord32((unsigned int)(key >> 23));
    }
    __syncthreads();

    int myc = (t < NSEL) ? (t >> 4) : -1;
    int mya = (t < NSEL) ? lsa[t] : -1;
    int myp = (t < NSEL) ? lsp[t] : -1;

    int fullowner = t;
    double fullsum = 0.0;
    if (t < NSEL) {
        for (int j = 0; j < NSEL; ++j) {
            if ((j >> 4) == myc && lsa[j] == mya && lsp[j] == myp) {
                if (j < fullowner) fullowner = j;
                fullsum += (double)lsv[j];
            }
        }
    }
    red[t] = (t < NSEL && fullowner == t) ? fullsum : 0.0;
    __syncthreads();
    for (int off = 128; off; off >>= 1) {
        if (t < off) red[t] = fmax(red[t], red[t + off]);
        __syncthreads();
    }
    if (t == 0) smx = red[0];
    __syncthreads();
    double mx = smx;

    int gowner = t;
    double rv = 0.0, tv = 0.0;
    if (t < NSEL) {
        int myb = myc & 3;
        for (int j = 0; j < NSEL; ++j) {
            int jc = j >> 4;
            if ((jc & 3) == myb && lsa[j] == mya && lsp[j] == myp) {
                if (j < gowner) gowner = j;
                if (jc < 4) rv += (double)lsv[j]; else tv += (double)lsv[j];
            }
        }
    }

    const double EPS = 1e-12;
    double bg_term = -log1p(-EPS);

    double extra = 0.0;
    if (t < NSEL && gowner == t) {
        double r = rv / mx, tt = tv / mx;
        double rc = r;
        if (rc < EPS) rc = EPS;
        if (rc > 1.0) rc = 1.0;
        double lr = log(rc);  if (lr < -100.0) lr = -100.0;
        double l1 = (rc >= 1.0) ? -100.0 : log1p(-rc);
        if (l1 < -100.0) l1 = -100.0;
        double term = -(tt * lr + (1.0 - tt) * l1);
        extra = term - bg_term;
    }

    red[t] = extra;
    __syncthreads();
    for (int off = 128; off; off >>= 1) {
        if (t < off) red[t] += red[t + off];
        __syncthreads();
    }
    if (t == 0) {
        const double count = 33554432.0;  // 4 * 256 * 32768
        double total = count * bg_term + red[0];
        out[0] = (float)(total / count);
    }
}

// ---------- launch ----------
extern "C" void kernel_launch(void* const* d_in, const int* in_sizes, int n_in,
                              void* d_out, int out_size, void* d_ws, size_t ws_size,
                              hipStream_t stream) {
    const float* recon  = (const float*)d_in[0];
    const float* target = (const float*)d_in[1];
    const float* d      = (const float*)d_in[2];
    char* ws = (char*)d_ws;
    float* d_t                    = (float*)(ws);                        // 512 KB
    float* res0                   = (float*)(ws + 524288);               // 1 MB
    float* res1                   = (float*)(ws + 1572864);              // 1 MB
    unsigned long long* mkey      = (unsigned long long*)(ws + 2621440); // 2 MB
    unsigned long long* stepkey   = (unsigned long long*)(ws + 4718592); // 1 KB
    ushort_t* d1g                 = (ushort_t*)(ws + 4719616);           // 256 KB
    ushort_t* d2g                 = (ushort_t*)(ws + 4981760);           // 256 KB
    ushort_t* d3g                 = (ushort_t*)(ws + 5243904);           // 256 KB
    float* out = (float*)d_out;

    hipLaunchKernelGGL(prep_kernel, dim3(NATOMS + 33), dim3(256), 0, stream,
                       recon, target, d, d_t, d1g, d2g, d3g, res0, res1, mkey, stepkey);
    hipLaunchKernelGGL(init_mfma, dim3(256, NCHAN), dim3(256), 0, stream,
                       res0, d1g, d2g, d3g, mkey, stepkey);
    for (int k = 0; k < NSTEPS - 1; ++k) {
        float* cur  = (k & 1) ? res1 : res0;
        float* next = (k & 1) ? res0 : res1;
        hipLaunchKernelGGL(step_kernel, dim3(384), dim3(256), 0, stream,
                           cur, next, d_t, d1g, d2g, d3g, mkey, stepkey, k);
    }
    hipLaunchKernelGGL(loss_kernel, dim3(1), dim3(256), 0, stream,
                       stepkey, out);
}